// Round 1
// baseline (324.066 us; speedup 1.0000x reference)
//
#include <hip/hip_runtime.h>

#define BITS 28
#define LZC_W 5

__global__ __launch_bounds__(256) void lzc28_kernel(const float* __restrict__ X,
                                                    float* __restrict__ out,
                                                    int n_rows) {
    const int stride = gridDim.x * blockDim.x;
    for (int r = blockIdx.x * blockDim.x + threadIdx.x; r < n_rows; r += stride) {
        // Row base is 16B-aligned: 28 floats = 112 B = 7 * 16 B.
        const float4* row = reinterpret_cast<const float4*>(X + (size_t)r * BITS);
        unsigned mask = 0u;
#pragma unroll
        for (int j = 0; j < 7; ++j) {
            float4 v = row[j];
            const int c = j * 4;
            mask |= (v.x > 0.5f ? 1u : 0u) << (27 - c);
            mask |= (v.y > 0.5f ? 1u : 0u) << (26 - c);
            mask |= (v.z > 0.5f ? 1u : 0u) << (27 - 2 - c);
            mask |= (v.w > 0.5f ? 1u : 0u) << (27 - 3 - c);
        }
        // lzc = index of first set bit scanning from bit 27 down; 28 if none.
        unsigned lzc = (mask == 0u) ? 28u : (unsigned)(__clz((int)mask) - 4);
        float* o = out + (size_t)r * LZC_W;
        o[0] = (float)((lzc >> 4) & 1u);
        o[1] = (float)((lzc >> 3) & 1u);
        o[2] = (float)((lzc >> 2) & 1u);
        o[3] = (float)((lzc >> 1) & 1u);
        o[4] = (float)(lzc & 1u);
    }
}

extern "C" void kernel_launch(void* const* d_in, const int* in_sizes, int n_in,
                              void* d_out, int out_size, void* d_ws, size_t ws_size,
                              hipStream_t stream) {
    const float* X = (const float*)d_in[0];
    float* out = (float*)d_out;
    const int n_rows = in_sizes[0] / BITS;  // 2,097,152

    const int block = 256;
    // Memory-bound: cap grid at ~2048 blocks, grid-stride the rest (4 rows/thread).
    int grid = 2048;
    lzc28_kernel<<<grid, block, 0, stream>>>(X, out, n_rows);
}

// Round 6
// 323.312 us; speedup vs baseline: 1.0023x; 1.0023x over previous
//
#include <hip/hip_runtime.h>

#define BITS 28
#define LZC_W 5
#define ROWS 256          // rows per block tile (= blockDim.x)
#define LSTRIDE 29        // padded LDS row stride in floats (coprime with 32 banks)

__global__ __launch_bounds__(256) void lzc28_kernel(const float* __restrict__ X,
                                                    float* __restrict__ out,
                                                    int n_tiles) {
    __shared__ float lx[ROWS * LSTRIDE];   // 29696 B
    __shared__ float lo[ROWS * LZC_W];     //  5120 B

    const int t = threadIdx.x;

    for (int tile = blockIdx.x; tile < n_tiles; tile += gridDim.x) {
        const size_t base_row = (size_t)tile * ROWS;

        // ---- Phase A: coalesced global -> LDS (padded scatter) ----
        // Tile = 1792 float4 chunks; thread t takes chunks t + k*256.
        // Each wave instruction reads 64 consecutive float4 = 1024 B contiguous.
        const float4* __restrict__ Xv =
            reinterpret_cast<const float4*>(X) + base_row * 7;
        float4 v[7];
#pragma unroll
        for (int k = 0; k < 7; ++k) v[k] = Xv[t + k * 256];
#pragma unroll
        for (int k = 0; k < 7; ++k) {
            const int g   = t + k * 256;     // chunk index within tile
            const int row = g / 7;           // compile-time magic-mul
            const int col = g - row * 7;
            float* dst = &lx[row * LSTRIDE + col * 4];
            dst[0] = v[k].x; dst[1] = v[k].y; dst[2] = v[k].z; dst[3] = v[k].w;
        }
        __syncthreads();

        // ---- Phase B: per-thread row -> 28-bit mask -> clz -> 5 bits ----
        const float* r = &lx[t * LSTRIDE];   // stride 29: <=2 lanes/bank, free
        unsigned mask = 0u;
#pragma unroll
        for (int c = 0; c < BITS; ++c)
            mask |= (r[c] > 0.5f ? 1u : 0u) << (27 - c);
        const unsigned lzc = (mask == 0u) ? 28u : (unsigned)(__clz((int)mask) - 4);
#pragma unroll
        for (int b = 0; b < LZC_W; ++b)
            lo[t * LZC_W + b] = (float)((lzc >> (4 - b)) & 1u);
        __syncthreads();

        // ---- Phase C: coalesced LDS -> global store (1280 contiguous floats) ----
        float* __restrict__ o = out + base_row * LZC_W;
#pragma unroll
        for (int k = 0; k < LZC_W; ++k) o[t + k * 256] = lo[t + k * 256];
        // No extra barrier needed: next iter's lx writes are fenced from this
        // iter's lx reads by the Phase-B barrier, and next iter's lo writes by
        // its own Phase-A barrier (all threads must finish Phase C to reach it).
    }
}

extern "C" void kernel_launch(void* const* d_in, const int* in_sizes, int n_in,
                              void* d_out, int out_size, void* d_ws, size_t ws_size,
                              hipStream_t stream) {
    const float* X = (const float*)d_in[0];
    float* out = (float*)d_out;
    const int n_rows  = in_sizes[0] / BITS;        // 2,097,152
    const int n_tiles = (n_rows + ROWS - 1) / ROWS; // 8192 (exact)

    // One tile per block; LDS ~34 KiB -> 4 blocks/CU, 16 waves/CU.
    lzc28_kernel<<<n_tiles, ROWS, 0, stream>>>(X, out, n_tiles);
}